// Round 3
// baseline (420.899 us; speedup 1.0000x reference)
//
#include <hip/hip_runtime.h>

// token shape (b=4, c=64, n=25, h=64, w=64), u=v=5
// Unfolded: S = 320 rows, D = 20480 features per batch.
// Flat addr of (b, s=(h,u), d=(c,v,w)): b*6553600 + c*102400 + (u*5+v)*4096 + h*64 + w

#define STR_B 6553600
#define STR_C 102400
#define STR_N 4096
#define STR_H 64

typedef __bf16 bf16x8 __attribute__((ext_vector_type(8)));
typedef float f32x4 __attribute__((ext_vector_type(4)));
typedef unsigned int u32x4 __attribute__((ext_vector_type(4)));

__device__ __forceinline__ int taddr(int b, int s, int d) {
    int h = s / 5, u = s % 5;
    int c = d / 320;
    int r = d % 320;
    int v = r >> 6;
    int w = r & 63;
    return b * STR_B + c * STR_C + (u * 5 + v) * STR_N + h * STR_H + w;
}

__device__ __forceinline__ unsigned short f2bf(float f) {
    unsigned int u = __float_as_uint(f);
    u += 0x7fffu + ((u >> 16) & 1u);
    return (unsigned short)(u >> 16);
}

__device__ __forceinline__ u32x4 pack8(float4 v0, float4 v1) {
    u32x4 w;
    w.x = (unsigned)f2bf(v0.x) | ((unsigned)f2bf(v0.y) << 16);
    w.y = (unsigned)f2bf(v0.z) | ((unsigned)f2bf(v0.w) << 16);
    w.z = (unsigned)f2bf(v1.x) | ((unsigned)f2bf(v1.y) << 16);
    w.w = (unsigned)f2bf(v1.z) | ((unsigned)f2bf(v1.w) << 16);
    return w;
}

// async global->LDS, 16B per lane; LDS dest must be wave-uniform base + lane*16
__device__ __forceinline__ void gload_lds16(const void* g, void* l) {
    __builtin_amdgcn_global_load_lds(
        (const __attribute__((address_space(1))) unsigned int*)g,
        (__attribute__((address_space(3))) unsigned int*)l,
        16, 0, 0);
}

// =============== FAST PATH ===============

// K1: streaming bf16 convert of Q,K into unfolded-contiguous [b*320][20480],
// UNNORMALIZED, with a detached per-row sumsq reduction -> qinv/kinv scalars.
// The store no longer depends on the block reduction, so nothing is live
// across a barrier (the old version rematerialized all loads: VGPR=24).
// Normalization is applied in scores2's epilogue (linear in the split-K sum).
// Q/K are never re-read after this kernel -> non-temporal loads.
__global__ __launch_bounds__(1024) void qk_prep_kernel(
        const float* __restrict__ q, const float* __restrict__ k,
        unsigned short* __restrict__ qb, unsigned short* __restrict__ kb,
        float* __restrict__ qinv, float* __restrict__ kinv) {
    int row = blockIdx.x;
    const float* src = (row < 1280) ? q : k;
    unsigned short* dst = (row < 1280) ? qb : kb;
    float* dinv = (row < 1280) ? qinv : kinv;
    int rr = (row < 1280) ? row : row - 1280;
    int b = rr / 320, s = rr % 320;
    int tid = threadIdx.x;
    unsigned short* drow = dst + (size_t)rr * 20480;
    float ss = 0.f;
#pragma unroll
    for (int p = 0; p < 5; ++p) {
        int d = (p * 1024 + tid) * 4;   // 16B aligned, within one 64-w chunk
        f32x4 v = __builtin_nontemporal_load((const f32x4*)(src + taddr(b, s, d)));
        ushort4 w;
        w.x = f2bf(v.x);
        w.y = f2bf(v.y);
        w.z = f2bf(v.z);
        w.w = f2bf(v.w);
        *(ushort4*)(drow + d) = w;
        ss += v.x * v.x + v.y * v.y + v.z * v.z + v.w * v.w;
    }
#pragma unroll
    for (int off = 32; off > 0; off >>= 1) ss += __shfl_xor(ss, off, 64);
    __shared__ float part[16];
    if ((tid & 63) == 0) part[tid >> 6] = ss;
    __syncthreads();
    if (tid == 0) {
        float tot = 0.f;
#pragma unroll
        for (int i = 0; i < 16; ++i) tot += part[i];
        dinv[rr] = 1.f / fmaxf(sqrtf(tot), 1e-12f);
    }
}

// K2: scores = (Qb @ Kb^T) * qinv[s] * kinv[t]. 64x64 causal tiles, BK=32,
// split-K=20 atomics. global_load_lds staging, XOR chunk swizzle (2-way banks).
#define SPLIT 20
#define KC (20480 / SPLIT)

__global__ __launch_bounds__(256) void scores2_kernel(
        const unsigned short* __restrict__ qb, const unsigned short* __restrict__ kb,
        const float* __restrict__ qinv, const float* __restrict__ kinv,
        float* __restrict__ att) {
    __shared__ unsigned short lds_a[64 * 32];
    __shared__ unsigned short lds_b[64 * 32];
    int b = blockIdx.y;
    int tileid = blockIdx.x / SPLIT;
    int chunk = blockIdx.x % SPLIT;
    int si = 0, rem = tileid;
    while (rem > si) { rem -= (si + 1); ++si; }
    int ti = rem;
    int s0 = si * 64, t0 = ti * 64;

    int tid = threadIdx.x;
    int r = tid >> 2, cl = tid & 3;
    int cg = cl ^ ((r >> 1) & 3);           // global chunk this thread stages
    const unsigned short* ga = qb + (size_t)(b * 320 + s0 + r) * 20480 + chunk * KC + cg * 8;
    const unsigned short* gk = kb + (size_t)(b * 320 + t0 + r) * 20480 + chunk * KC + cg * 8;
    unsigned short* la = &lds_a[tid * 8];
    unsigned short* lb = &lds_b[tid * 8];

    int lane = tid & 63, wid = tid >> 6;
    int wy = wid >> 1, wx = wid & 1;
    int quad = lane >> 4, l15 = lane & 15;

    f32x4 acc[2][2] = {};
    for (int kk = 0; kk < KC; kk += 32) {
        gload_lds16(ga, la);
        gload_lds16(gk, lb);
        ga += 32; gk += 32;
        __syncthreads();
        bf16x8 af[2], bf[2];
#pragma unroll
        for (int t = 0; t < 2; ++t) {
            int ra = wy * 32 + t * 16 + l15;
            int ca = quad ^ ((ra >> 1) & 3);
            af[t] = __builtin_bit_cast(bf16x8, *(const u32x4*)&lds_a[ra * 32 + ca * 8]);
            int rb = wx * 32 + t * 16 + l15;
            int cb = quad ^ ((rb >> 1) & 3);
            bf[t] = __builtin_bit_cast(bf16x8, *(const u32x4*)&lds_b[rb * 32 + cb * 8]);
        }
        __syncthreads();
#pragma unroll
        for (int tm = 0; tm < 2; ++tm)
#pragma unroll
            for (int tn = 0; tn < 2; ++tn)
                acc[tm][tn] = __builtin_amdgcn_mfma_f32_16x16x32_bf16(
                    af[tm], bf[tn], acc[tm][tn], 0, 0, 0);
    }
    float ki[2];
#pragma unroll
    for (int tn = 0; tn < 2; ++tn)
        ki[tn] = kinv[b * 320 + t0 + wx * 32 + tn * 16 + l15];
#pragma unroll
    for (int tm = 0; tm < 2; ++tm)
#pragma unroll
        for (int tn = 0; tn < 2; ++tn)
#pragma unroll
            for (int i = 0; i < 4; ++i) {
                int s = s0 + wy * 32 + tm * 16 + quad * 4 + i;
                int t = t0 + wx * 32 + tn * 16 + l15;
                if (t <= s)
                    atomicAdd(&att[(b * 320 + s) * 320 + t],
                              acc[tm][tn][i] * qinv[b * 320 + s] * ki[tn]);
            }
}

// K3: causal softmax, P as bf16 (zeros above diagonal)
__global__ __launch_bounds__(256) void softmax_kernel(
        const float* __restrict__ att, unsigned short* __restrict__ p) {
    int row = blockIdx.x * 4 + (threadIdx.x >> 6);
    int lane = threadIdx.x & 63;
    int b = row / 320, s = row % 320;
    const float* ar = att + (b * 320 + s) * 320;
    float v[5];
    float m = -1e30f;
#pragma unroll
    for (int j = 0; j < 5; ++j) {
        int t = lane + j * 64;
        v[j] = (t <= s) ? ar[t] : -1e30f;
        m = fmaxf(m, v[j]);
    }
#pragma unroll
    for (int off = 32; off > 0; off >>= 1) m = fmaxf(m, __shfl_xor(m, off, 64));
    float sum = 0.f;
#pragma unroll
    for (int j = 0; j < 5; ++j) {
        int t = lane + j * 64;
        v[j] = (t <= s) ? __expf(v[j] - m) : 0.f;
        sum += v[j];
    }
#pragma unroll
    for (int off = 32; off > 0; off >>= 1) sum += __shfl_xor(sum, off, 64);
    float inv = 1.f / sum;
    unsigned short* pr = p + (b * 320 + s) * 320;
#pragma unroll
    for (int j = 0; j < 5; ++j) {
        int t = lane + j * 64;
        pr[t] = f2bf(v[j] * inv);
    }
}

// K3b: one-shot transpose-convert V -> bf16 V^T [b][d=20480][t=320]
__global__ __launch_bounds__(256) void v_prep_kernel(
        const float* __restrict__ vin, unsigned short* __restrict__ vT) {
    __shared__ unsigned short lt[64 * 68];
    int b = blockIdx.z;
    int t0 = blockIdx.y * 64;
    int d0 = blockIdx.x * 64;
    int tid = threadIdx.x;
    int tl0 = tid >> 4;
    int dl = (tid & 15) * 4;
#pragma unroll
    for (int p = 0; p < 4; ++p) {
        int tl = tl0 + p * 16;
        float4 v = *(const float4*)(vin + taddr(b, t0 + tl, d0 + dl));
        lt[(dl + 0) * 68 + tl] = f2bf(v.x);
        lt[(dl + 1) * 68 + tl] = f2bf(v.y);
        lt[(dl + 2) * 68 + tl] = f2bf(v.z);
        lt[(dl + 3) * 68 + tl] = f2bf(v.w);
    }
    __syncthreads();
    int tc = (tid & 15) * 4;
#pragma unroll
    for (int p = 0; p < 4; ++p) {
        int dr = tl0 + p * 16;
        ushort4 w;
        w.x = lt[dr * 68 + tc + 0];
        w.y = lt[dr * 68 + tc + 1];
        w.z = lt[dr * 68 + tc + 2];
        w.w = lt[dr * 68 + tc + 3];
        *(ushort4*)(vT + (size_t)(b * 20480 + d0 + dr) * 320 + t0 + tc) = w;
    }
}

// K4: out = P @ V + residual, both operands bf16, global_load_lds staging
__global__ __launch_bounds__(256) void pv2_kernel(
        const unsigned short* __restrict__ p, const unsigned short* __restrict__ vT,
        const float* __restrict__ vin, float* __restrict__ out) {
    __shared__ unsigned short lds_a[64 * 32];
    __shared__ unsigned short lds_b[64 * 32];
    int b = blockIdx.z;
    int s0 = blockIdx.y * 64;
    int d0 = blockIdx.x * 64;
    int tid = threadIdx.x;
    int r = tid >> 2, cl = tid & 3;
    int cg = cl ^ ((r >> 1) & 3);
    const unsigned short* ga = p + (size_t)(b * 320 + s0 + r) * 320 + cg * 8;
    const unsigned short* gv = vT + (size_t)(b * 20480 + d0 + r) * 320 + cg * 8;
    unsigned short* la = &lds_a[tid * 8];
    unsigned short* lb = &lds_b[tid * 8];

    int lane = tid & 63, wid = tid >> 6;
    int wy = wid >> 1, wx = wid & 1;
    int quad = lane >> 4, l15 = lane & 15;

    f32x4 acc[2][2] = {};
    int nk = (s0 + 64) >> 5;  // causal: P zero beyond s0+64
    for (int kc = 0; kc < nk; ++kc) {
        gload_lds16(ga, la);
        gload_lds16(gv, lb);
        ga += 32; gv += 32;
        __syncthreads();
        bf16x8 af[2], bf[2];
#pragma unroll
        for (int t = 0; t < 2; ++t) {
            int ra = wy * 32 + t * 16 + l15;
            int ca = quad ^ ((ra >> 1) & 3);
            af[t] = __builtin_bit_cast(bf16x8, *(const u32x4*)&lds_a[ra * 32 + ca * 8]);
            int rb = wx * 32 + t * 16 + l15;
            int cb = quad ^ ((rb >> 1) & 3);
            bf[t] = __builtin_bit_cast(bf16x8, *(const u32x4*)&lds_b[rb * 32 + cb * 8]);
        }
        __syncthreads();
#pragma unroll
        for (int tm = 0; tm < 2; ++tm)
#pragma unroll
            for (int tn = 0; tn < 2; ++tn)
                acc[tm][tn] = __builtin_amdgcn_mfma_f32_16x16x32_bf16(
                    af[tm], bf[tn], acc[tm][tn], 0, 0, 0);
    }
#pragma unroll
    for (int tm = 0; tm < 2; ++tm)
#pragma unroll
        for (int tn = 0; tn < 2; ++tn)
#pragma unroll
            for (int i = 0; i < 4; ++i) {
                int s = s0 + wy * 32 + tm * 16 + quad * 4 + i;
                int d = d0 + wx * 32 + tn * 16 + l15;
                int a = taddr(b, s, d);
                out[a] = acc[tm][tn][i] + vin[a];
            }
}

// =============== FALLBACK (round-1 pipeline, ~2.5 MB ws) ===============

__global__ __launch_bounds__(256) void norm_kernel(
        const float* __restrict__ q, const float* __restrict__ k,
        float* __restrict__ qinv, float* __restrict__ kinv) {
    int row = blockIdx.x;
    const float* src = (row < 1280) ? q : k;
    float* dst = (row < 1280) ? qinv : kinv;
    int rr = (row < 1280) ? row : row - 1280;
    int b = rr / 320, s = rr % 320;
    int tid = threadIdx.x;
    float ss = 0.f;
#pragma unroll
    for (int p = 0; p < 20; ++p) {
        int kk = (p * 256 + tid) * 4;
        const float4 v = *(const float4*)(src + taddr(b, s, kk));
        ss += v.x * v.x + v.y * v.y + v.z * v.z + v.w * v.w;
    }
#pragma unroll
    for (int off = 32; off > 0; off >>= 1) ss += __shfl_xor(ss, off, 64);
    __shared__ float part[4];
    if ((tid & 63) == 0) part[tid >> 6] = ss;
    __syncthreads();
    if (tid == 0) {
        float tot = part[0] + part[1] + part[2] + part[3];
        dst[rr] = 1.f / fmaxf(sqrtf(tot), 1e-12f);
    }
}

#define CHUNKS 10
#define KCHUNK 2048

__global__ __launch_bounds__(256) void scores_kernel(
        const float* __restrict__ q, const float* __restrict__ kmat,
        const float* __restrict__ qinv, const float* __restrict__ kinv,
        float* __restrict__ att) {
    __shared__ unsigned short lds_a[64 * 40];
    __shared__ unsigned short lds_b[64 * 40];
    int b = blockIdx.y;
    int tileid = blockIdx.x / CHUNKS;
    int chunk = blockIdx.x % CHUNKS;
    int si = 0, rem = tileid;
    while (rem > si) { rem -= (si + 1); ++si; }
    int ti = rem;
    int s0 = si * 64, t0 = ti * 64;
    int tid = threadIdx.x;
    int r = tid >> 2, koff = (tid & 3) * 8;
    int lane = tid & 63, wid = tid >> 6;
    int wy = wid >> 1, wx = wid & 1;
    int quad = lane >> 4, l15 = lane & 15;
    f32x4 acc[2][2] = {};
    for (int kk = 0; kk < KCHUNK; kk += 32) {
        int kg = chunk * KCHUNK + kk + koff;
        const float4* pa = (const float4*)(q + taddr(b, s0 + r, kg));
        *(u32x4*)&lds_a[r * 40 + koff] = pack8(pa[0], pa[1]);
        const float4* pb = (const float4*)(kmat + taddr(b, t0 + r, kg));
        *(u32x4*)&lds_b[r * 40 + koff] = pack8(pb[0], pb[1]);
        __syncthreads();
        bf16x8 af[2], bf[2];
#pragma unroll
        for (int t = 0; t < 2; ++t) {
            af[t] = __builtin_bit_cast(bf16x8,
                *(const u32x4*)&lds_a[(wy * 32 + t * 16 + l15) * 40 + quad * 8]);
            bf[t] = __builtin_bit_cast(bf16x8,
                *(const u32x4*)&lds_b[(wx * 32 + t * 16 + l15) * 40 + quad * 8]);
        }
#pragma unroll
        for (int tm = 0; tm < 2; ++tm)
#pragma unroll
            for (int tn = 0; tn < 2; ++tn)
                acc[tm][tn] = __builtin_amdgcn_mfma_f32_16x16x32_bf16(
                    af[tm], bf[tn], acc[tm][tn], 0, 0, 0);
        __syncthreads();
    }
#pragma unroll
    for (int tm = 0; tm < 2; ++tm)
#pragma unroll
        for (int tn = 0; tn < 2; ++tn)
#pragma unroll
            for (int i = 0; i < 4; ++i) {
                int s = s0 + wy * 32 + tm * 16 + quad * 4 + i;
                int t = t0 + wx * 32 + tn * 16 + l15;
                if (t <= s) {
                    float val = acc[tm][tn][i] * qinv[b * 320 + s] * kinv[b * 320 + t];
                    atomicAdd(&att[(b * 320 + s) * 320 + t], val);
                }
            }
}

__global__ __launch_bounds__(256) void pv_kernel(
        const unsigned short* __restrict__ p, const float* __restrict__ vin,
        float* __restrict__ out) {
    __shared__ unsigned short lds_a[64 * 40];
    __shared__ unsigned short lds_b[64 * 40];
    int b = blockIdx.z;
    int s0 = blockIdx.y * 64;
    int d0 = blockIdx.x * 64;
    int tid = threadIdx.x;
    int lane = tid & 63, wid = tid >> 6;
    int wy = wid >> 1, wx = wid & 1;
    int quad = lane >> 4, l15 = lane & 15;
    int ar = tid >> 2, akoff = (tid & 3) * 8;
    int bt = tid >> 4;
    int bd = (tid & 15) * 4;
    f32x4 acc[2][2] = {};
    int nk = (s0 + 64) >> 5;
    for (int kc = 0; kc < nk; ++kc) {
        int t0k = kc * 32;
        u32x4 aw = *(const u32x4*)(p + ((b * 320 + s0 + ar) * 320 + t0k + akoff));
        *(u32x4*)&lds_a[ar * 40 + akoff] = aw;
#pragma unroll
        for (int pp = 0; pp < 2; ++pp) {
            int tt = bt + pp * 16;
            float4 v = *(const float4*)(vin + taddr(b, t0k + tt, d0 + bd));
            lds_b[(bd + 0) * 40 + tt] = f2bf(v.x);
            lds_b[(bd + 1) * 40 + tt] = f2bf(v.y);
            lds_b[(bd + 2) * 40 + tt] = f2bf(v.z);
            lds_b[(bd + 3) * 40 + tt] = f2bf(v.w);
        }
        __syncthreads();
        bf16x8 af[2], bf[2];
#pragma unroll
        for (int t = 0; t < 2; ++t) {
            af[t] = __builtin_bit_cast(bf16x8,
                *(const u32x4*)&lds_a[(wy * 32 + t * 16 + l15) * 40 + quad * 8]);
            bf[t] = __builtin_bit_cast(bf16x8,
                *(const u32x4*)&lds_b[(wx * 32 + t * 16 + l15) * 40 + quad * 8]);
        }
#pragma unroll
        for (int tm = 0; tm < 2; ++tm)
#pragma unroll
            for (int tn = 0; tn < 2; ++tn)
                acc[tm][tn] = __builtin_amdgcn_mfma_f32_16x16x32_bf16(
                    af[tm], bf[tn], acc[tm][tn], 0, 0, 0);
        __syncthreads();
    }
#pragma unroll
    for (int tm = 0; tm < 2; ++tm)
#pragma unroll
        for (int tn = 0; tn < 2; ++tn)
#pragma unroll
            for (int i = 0; i < 4; ++i) {
                int s = s0 + wy * 32 + tm * 16 + quad * 4 + i;
                int d = d0 + wx * 32 + tn * 16 + l15;
                int a = taddr(b, s, d);
                out[a] = acc[tm][tn][i] + vin[a];
            }
}

extern "C" void kernel_launch(void* const* d_in, const int* in_sizes, int n_in,
                              void* d_out, int out_size, void* d_ws, size_t ws_size,
                              hipStream_t stream) {
    const float* q = (const float*)d_in[0];
    const float* k = (const float*)d_in[1];
    const float* v = (const float*)d_in[2];
    float* out = (float*)d_out;
    char* ws = (char*)d_ws;

    const size_t QB_BYTES = (size_t)4 * 320 * 20480 * 2;     // 52,428,800
    const size_t ATT_BYTES = (size_t)4 * 320 * 320 * 4;      // 1,638,400
    const size_t P_BYTES = (size_t)4 * 320 * 320 * 2;        // 819,200
    const size_t INV_BYTES = (size_t)4 * 320 * 4;            // 5,120 per array
    const size_t NEED = 2 * QB_BYTES + ATT_BYTES + P_BYTES + 2 * INV_BYTES;

    if (ws_size >= NEED) {
        unsigned short* qb = (unsigned short*)ws;
        unsigned short* kb = (unsigned short*)(ws + QB_BYTES);
        float* att = (float*)(ws + 2 * QB_BYTES);
        unsigned short* p = (unsigned short*)(ws + 2 * QB_BYTES + ATT_BYTES);
        float* qinv = (float*)(ws + 2 * QB_BYTES + ATT_BYTES + P_BYTES);
        float* kinv = (float*)(ws + 2 * QB_BYTES + ATT_BYTES + P_BYTES + INV_BYTES);
        unsigned short* vT = (unsigned short*)ws;  // overlaps qb; written after scores2

        qk_prep_kernel<<<2560, 1024, 0, stream>>>(q, k, qb, kb, qinv, kinv);
        hipMemsetAsync(att, 0, ATT_BYTES, stream);
        scores2_kernel<<<dim3(15 * SPLIT, 4), 256, 0, stream>>>(qb, kb, qinv, kinv, att);
        softmax_kernel<<<320, 256, 0, stream>>>(att, p);
        v_prep_kernel<<<dim3(320, 5, 4), 256, 0, stream>>>(v, vT);
        pv2_kernel<<<dim3(320, 5, 4), 256, 0, stream>>>(p, vT, v, out);
    } else {
        float* qinv = (float*)ws;
        float* kinv = (float*)(ws + 5120);
        float* att = (float*)(ws + 10240);
        unsigned short* p = (unsigned short*)(ws + 10240 + ATT_BYTES);

        norm_kernel<<<2560, 256, 0, stream>>>(q, k, qinv, kinv);
        hipMemsetAsync(att, 0, ATT_BYTES, stream);
        scores_kernel<<<dim3(15 * CHUNKS, 4), 256, 0, stream>>>(q, k, qinv, kinv, att);
        softmax_kernel<<<320, 256, 0, stream>>>(att, p);
        pv_kernel<<<dim3(320, 5, 4), 256, 0, stream>>>(p, v, out);
    }
}

// Round 4
// 414.218 us; speedup vs baseline: 1.0161x; 1.0161x over previous
//
#include <hip/hip_runtime.h>

// token shape (b=4, c=64, n=25, h=64, w=64), u=v=5
// Unfolded: S = 320 rows, D = 20480 features per batch.
// Flat addr of (b, s=(h,u), d=(c,v,w)): b*6553600 + c*102400 + (u*5+v)*4096 + h*64 + w

#define STR_B 6553600
#define STR_C 102400
#define STR_N 4096
#define STR_H 64

typedef __bf16 bf16x8 __attribute__((ext_vector_type(8)));
typedef float f32x4 __attribute__((ext_vector_type(4)));
typedef unsigned int u32x4 __attribute__((ext_vector_type(4)));

__device__ __forceinline__ int taddr(int b, int s, int d) {
    int h = s / 5, u = s % 5;
    int c = d / 320;
    int r = d % 320;
    int v = r >> 6;
    int w = r & 63;
    return b * STR_B + c * STR_C + (u * 5 + v) * STR_N + h * STR_H + w;
}

__device__ __forceinline__ unsigned short f2bf(float f) {
    unsigned int u = __float_as_uint(f);
    u += 0x7fffu + ((u >> 16) & 1u);
    return (unsigned short)(u >> 16);
}

__device__ __forceinline__ u32x4 pack8(float4 v0, float4 v1) {
    u32x4 w;
    w.x = (unsigned)f2bf(v0.x) | ((unsigned)f2bf(v0.y) << 16);
    w.y = (unsigned)f2bf(v0.z) | ((unsigned)f2bf(v0.w) << 16);
    w.z = (unsigned)f2bf(v1.x) | ((unsigned)f2bf(v1.y) << 16);
    w.w = (unsigned)f2bf(v1.z) | ((unsigned)f2bf(v1.w) << 16);
    return w;
}

// async global->LDS, 16B per lane; LDS dest must be wave-uniform base + lane*16
__device__ __forceinline__ void gload_lds16(const void* g, void* l) {
    __builtin_amdgcn_global_load_lds(
        (const __attribute__((address_space(1))) unsigned int*)g,
        (__attribute__((address_space(3))) unsigned int*)l,
        16, 0, 0);
}

// fragment-load + 4 MFMA on one 64x32 LDS chunk pair (XOR chunk swizzle layout)
#define QK_STEP(LA, LB)                                                          \
    do {                                                                         \
        bf16x8 af[2], bf[2];                                                     \
        _Pragma("unroll")                                                        \
        for (int t = 0; t < 2; ++t) {                                            \
            int ra = wy * 32 + t * 16 + l15;                                     \
            int ca = quad ^ ((ra >> 1) & 3);                                     \
            af[t] = __builtin_bit_cast(bf16x8, *(const u32x4*)&LA[ra * 32 + ca * 8]); \
            int rb = wx * 32 + t * 16 + l15;                                     \
            int cb = quad ^ ((rb >> 1) & 3);                                     \
            bf[t] = __builtin_bit_cast(bf16x8, *(const u32x4*)&LB[rb * 32 + cb * 8]); \
        }                                                                        \
        _Pragma("unroll")                                                        \
        for (int tm = 0; tm < 2; ++tm)                                           \
            _Pragma("unroll")                                                    \
            for (int tn = 0; tn < 2; ++tn)                                       \
                acc[tm][tn] = __builtin_amdgcn_mfma_f32_16x16x32_bf16(           \
                    af[tm], bf[tn], acc[tm][tn], 0, 0, 0);                       \
    } while (0)

// =============== FAST PATH ===============

// K1: streaming bf16 convert of Q,K into unfolded-contiguous [b*320][20480],
// UNNORMALIZED, with a detached per-row sumsq reduction -> qinv/kinv scalars.
// Normalization is applied in scores2's epilogue (linear in the split-K sum).
// Q/K are never re-read after this kernel -> non-temporal loads.
__global__ __launch_bounds__(1024) void qk_prep_kernel(
        const float* __restrict__ q, const float* __restrict__ k,
        unsigned short* __restrict__ qb, unsigned short* __restrict__ kb,
        float* __restrict__ qinv, float* __restrict__ kinv) {
    int row = blockIdx.x;
    const float* src = (row < 1280) ? q : k;
    unsigned short* dst = (row < 1280) ? qb : kb;
    float* dinv = (row < 1280) ? qinv : kinv;
    int rr = (row < 1280) ? row : row - 1280;
    int b = rr / 320, s = rr % 320;
    int tid = threadIdx.x;
    unsigned short* drow = dst + (size_t)rr * 20480;
    float ss = 0.f;
#pragma unroll
    for (int p = 0; p < 5; ++p) {
        int d = (p * 1024 + tid) * 4;   // 16B aligned, within one 64-w chunk
        f32x4 v = __builtin_nontemporal_load((const f32x4*)(src + taddr(b, s, d)));
        ushort4 w;
        w.x = f2bf(v.x);
        w.y = f2bf(v.y);
        w.z = f2bf(v.z);
        w.w = f2bf(v.w);
        *(ushort4*)(drow + d) = w;
        ss += v.x * v.x + v.y * v.y + v.z * v.z + v.w * v.w;
    }
#pragma unroll
    for (int off = 32; off > 0; off >>= 1) ss += __shfl_xor(ss, off, 64);
    __shared__ float part[16];
    if ((tid & 63) == 0) part[tid >> 6] = ss;
    __syncthreads();
    if (tid == 0) {
        float tot = 0.f;
#pragma unroll
        for (int i = 0; i < 16; ++i) tot += part[i];
        dinv[rr] = 1.f / fmaxf(sqrtf(tot), 1e-12f);
    }
}

// K2: scores = (Qb @ Kb^T) * qinv[s] * kinv[t]. 64x64 causal tiles, BK=32,
// split-K=20 atomics. Double-buffered global_load_lds: next chunk's stage is
// issued BEFORE consuming the current buffer, so the vmcnt(0) drain at the
// (single) barrier per step waits on a load that flew under ds_read+MFMA.
#define SPLIT 20
#define KC (20480 / SPLIT)

__global__ __launch_bounds__(256) void scores2_kernel(
        const unsigned short* __restrict__ qb, const unsigned short* __restrict__ kb,
        const float* __restrict__ qinv, const float* __restrict__ kinv,
        float* __restrict__ att) {
    __shared__ unsigned short lds_a0[64 * 32];
    __shared__ unsigned short lds_a1[64 * 32];
    __shared__ unsigned short lds_b0[64 * 32];
    __shared__ unsigned short lds_b1[64 * 32];
    int b = blockIdx.y;
    int tileid = blockIdx.x / SPLIT;
    int chunk = blockIdx.x % SPLIT;
    int si = 0, rem = tileid;
    while (rem > si) { rem -= (si + 1); ++si; }
    int ti = rem;
    int s0 = si * 64, t0 = ti * 64;

    int tid = threadIdx.x;
    int r = tid >> 2, cl = tid & 3;
    int cg = cl ^ ((r >> 1) & 3);           // global chunk this thread stages
    const unsigned short* gab = qb + (size_t)(b * 320 + s0 + r) * 20480 + chunk * KC + cg * 8;
    const unsigned short* gkb = kb + (size_t)(b * 320 + t0 + r) * 20480 + chunk * KC + cg * 8;
    unsigned short* la0 = &lds_a0[tid * 8];
    unsigned short* la1 = &lds_a1[tid * 8];
    unsigned short* lb0 = &lds_b0[tid * 8];
    unsigned short* lb1 = &lds_b1[tid * 8];

    int lane = tid & 63, wid = tid >> 6;
    int wy = wid >> 1, wx = wid & 1;
    int quad = lane >> 4, l15 = lane & 15;

    f32x4 acc[2][2] = {};
    gload_lds16(gab, la0);
    gload_lds16(gkb, lb0);
    __syncthreads();
    for (int kk = 0; kk < KC; kk += 64) {
        gload_lds16(gab + kk + 32, la1);
        gload_lds16(gkb + kk + 32, lb1);
        QK_STEP(lds_a0, lds_b0);
        __syncthreads();
        if (kk + 64 < KC) {
            gload_lds16(gab + kk + 64, la0);
            gload_lds16(gkb + kk + 64, lb0);
        }
        QK_STEP(lds_a1, lds_b1);
        __syncthreads();
    }
    float ki[2];
#pragma unroll
    for (int tn = 0; tn < 2; ++tn)
        ki[tn] = kinv[b * 320 + t0 + wx * 32 + tn * 16 + l15];
#pragma unroll
    for (int tm = 0; tm < 2; ++tm)
#pragma unroll
        for (int tn = 0; tn < 2; ++tn)
#pragma unroll
            for (int i = 0; i < 4; ++i) {
                int s = s0 + wy * 32 + tm * 16 + quad * 4 + i;
                int t = t0 + wx * 32 + tn * 16 + l15;
                if (t <= s)
                    atomicAdd(&att[(b * 320 + s) * 320 + t],
                              acc[tm][tn][i] * qinv[b * 320 + s] * ki[tn]);
            }
}

// K3: fused {causal softmax (blocks 0..319)} + {V -> bf16 V^T transpose
// (blocks 320..6719)} — independent ops, one dispatch.
__global__ __launch_bounds__(256) void softmax_vprep_kernel(
        const float* __restrict__ att, unsigned short* __restrict__ p,
        const float* __restrict__ vin, unsigned short* __restrict__ vT) {
    __shared__ unsigned short lt[64 * 68];
    int bid = blockIdx.x;
    int tid = threadIdx.x;
    if (bid < 320) {
        int row = bid * 4 + (tid >> 6);
        int lane = tid & 63;
        int b = row / 320, s = row % 320;
        const float* ar = att + (b * 320 + s) * 320;
        float v[5];
        float m = -1e30f;
#pragma unroll
        for (int j = 0; j < 5; ++j) {
            int t = lane + j * 64;
            v[j] = (t <= s) ? ar[t] : -1e30f;
            m = fmaxf(m, v[j]);
        }
#pragma unroll
        for (int off = 32; off > 0; off >>= 1) m = fmaxf(m, __shfl_xor(m, off, 64));
        float sum = 0.f;
#pragma unroll
        for (int j = 0; j < 5; ++j) {
            int t = lane + j * 64;
            v[j] = (t <= s) ? __expf(v[j] - m) : 0.f;
            sum += v[j];
        }
#pragma unroll
        for (int off = 32; off > 0; off >>= 1) sum += __shfl_xor(sum, off, 64);
        float inv = 1.f / sum;
        unsigned short* pr = p + (b * 320 + s) * 320;
#pragma unroll
        for (int j = 0; j < 5; ++j) {
            int t = lane + j * 64;
            pr[t] = f2bf(v[j] * inv);
        }
        return;
    }
    int idx = bid - 320;
    int d0 = (idx % 320) * 64;
    int t0 = ((idx / 320) % 5) * 64;
    int b = idx / 1600;
    int tl0 = tid >> 4;
    int dl = (tid & 15) * 4;
#pragma unroll
    for (int pp = 0; pp < 4; ++pp) {
        int tl = tl0 + pp * 16;
        float4 v = *(const float4*)(vin + taddr(b, t0 + tl, d0 + dl));
        lt[(dl + 0) * 68 + tl] = f2bf(v.x);
        lt[(dl + 1) * 68 + tl] = f2bf(v.y);
        lt[(dl + 2) * 68 + tl] = f2bf(v.z);
        lt[(dl + 3) * 68 + tl] = f2bf(v.w);
    }
    __syncthreads();
    int tc = (tid & 15) * 4;
#pragma unroll
    for (int pp = 0; pp < 4; ++pp) {
        int dr = tl0 + pp * 16;
        ushort4 w;
        w.x = lt[dr * 68 + tc + 0];
        w.y = lt[dr * 68 + tc + 1];
        w.z = lt[dr * 68 + tc + 2];
        w.w = lt[dr * 68 + tc + 3];
        *(ushort4*)(vT + (size_t)(b * 20480 + d0 + dr) * 320 + t0 + tc) = w;
    }
}

// K4: out = P @ V + residual, both operands bf16, double-buffered staging
// (nk is always even: nk = 2*(s0/64+1)).
__global__ __launch_bounds__(256) void pv2_kernel(
        const unsigned short* __restrict__ p, const unsigned short* __restrict__ vT,
        const float* __restrict__ vin, float* __restrict__ out) {
    __shared__ unsigned short lds_a0[64 * 32];
    __shared__ unsigned short lds_a1[64 * 32];
    __shared__ unsigned short lds_b0[64 * 32];
    __shared__ unsigned short lds_b1[64 * 32];
    int b = blockIdx.z;
    int s0 = blockIdx.y * 64;
    int d0 = blockIdx.x * 64;
    int tid = threadIdx.x;
    int r = tid >> 2, cl = tid & 3;
    int cg = cl ^ ((r >> 1) & 3);
    const unsigned short* gab = p + (size_t)(b * 320 + s0 + r) * 320 + cg * 8;
    const unsigned short* gvb = vT + (size_t)(b * 20480 + d0 + r) * 320 + cg * 8;
    unsigned short* la0 = &lds_a0[tid * 8];
    unsigned short* la1 = &lds_a1[tid * 8];
    unsigned short* lb0 = &lds_b0[tid * 8];
    unsigned short* lb1 = &lds_b1[tid * 8];

    int lane = tid & 63, wid = tid >> 6;
    int wy = wid >> 1, wx = wid & 1;
    int quad = lane >> 4, l15 = lane & 15;

    f32x4 acc[2][2] = {};
    int nk = (s0 + 64) >> 5;  // causal: P zero beyond s0+64; always even
    gload_lds16(gab, la0);
    gload_lds16(gvb, lb0);
    __syncthreads();
    for (int kc = 0; kc < nk; kc += 2) {
        gload_lds16(gab + (kc + 1) * 32, la1);
        gload_lds16(gvb + (kc + 1) * 32, lb1);
        QK_STEP(lds_a0, lds_b0);
        __syncthreads();
        if (kc + 2 < nk) {
            gload_lds16(gab + (kc + 2) * 32, la0);
            gload_lds16(gvb + (kc + 2) * 32, lb0);
        }
        QK_STEP(lds_a1, lds_b1);
        __syncthreads();
    }
#pragma unroll
    for (int tm = 0; tm < 2; ++tm)
#pragma unroll
        for (int tn = 0; tn < 2; ++tn)
#pragma unroll
            for (int i = 0; i < 4; ++i) {
                int s = s0 + wy * 32 + tm * 16 + quad * 4 + i;
                int d = d0 + wx * 32 + tn * 16 + l15;
                int a = taddr(b, s, d);
                out[a] = acc[tm][tn][i] + vin[a];
            }
}

// =============== FALLBACK (round-1 pipeline, ~2.5 MB ws) ===============

__global__ __launch_bounds__(256) void norm_kernel(
        const float* __restrict__ q, const float* __restrict__ k,
        float* __restrict__ qinv, float* __restrict__ kinv) {
    int row = blockIdx.x;
    const float* src = (row < 1280) ? q : k;
    float* dst = (row < 1280) ? qinv : kinv;
    int rr = (row < 1280) ? row : row - 1280;
    int b = rr / 320, s = rr % 320;
    int tid = threadIdx.x;
    float ss = 0.f;
#pragma unroll
    for (int p = 0; p < 20; ++p) {
        int kk = (p * 256 + tid) * 4;
        const float4 v = *(const float4*)(src + taddr(b, s, kk));
        ss += v.x * v.x + v.y * v.y + v.z * v.z + v.w * v.w;
    }
#pragma unroll
    for (int off = 32; off > 0; off >>= 1) ss += __shfl_xor(ss, off, 64);
    __shared__ float part[4];
    if ((tid & 63) == 0) part[tid >> 6] = ss;
    __syncthreads();
    if (tid == 0) {
        float tot = part[0] + part[1] + part[2] + part[3];
        dst[rr] = 1.f / fmaxf(sqrtf(tot), 1e-12f);
    }
}

__global__ __launch_bounds__(256) void softmax_kernel(
        const float* __restrict__ att, unsigned short* __restrict__ p) {
    int row = blockIdx.x * 4 + (threadIdx.x >> 6);
    int lane = threadIdx.x & 63;
    int b = row / 320, s = row % 320;
    const float* ar = att + (b * 320 + s) * 320;
    float v[5];
    float m = -1e30f;
#pragma unroll
    for (int j = 0; j < 5; ++j) {
        int t = lane + j * 64;
        v[j] = (t <= s) ? ar[t] : -1e30f;
        m = fmaxf(m, v[j]);
    }
#pragma unroll
    for (int off = 32; off > 0; off >>= 1) m = fmaxf(m, __shfl_xor(m, off, 64));
    float sum = 0.f;
#pragma unroll
    for (int j = 0; j < 5; ++j) {
        int t = lane + j * 64;
        v[j] = (t <= s) ? __expf(v[j] - m) : 0.f;
        sum += v[j];
    }
#pragma unroll
    for (int off = 32; off > 0; off >>= 1) sum += __shfl_xor(sum, off, 64);
    float inv = 1.f / sum;
    unsigned short* pr = p + (b * 320 + s) * 320;
#pragma unroll
    for (int j = 0; j < 5; ++j) {
        int t = lane + j * 64;
        pr[t] = f2bf(v[j] * inv);
    }
}

#define CHUNKS 10
#define KCHUNK 2048

__global__ __launch_bounds__(256) void scores_kernel(
        const float* __restrict__ q, const float* __restrict__ kmat,
        const float* __restrict__ qinv, const float* __restrict__ kinv,
        float* __restrict__ att) {
    __shared__ unsigned short lds_a[64 * 40];
    __shared__ unsigned short lds_b[64 * 40];
    int b = blockIdx.y;
    int tileid = blockIdx.x / CHUNKS;
    int chunk = blockIdx.x % CHUNKS;
    int si = 0, rem = tileid;
    while (rem > si) { rem -= (si + 1); ++si; }
    int ti = rem;
    int s0 = si * 64, t0 = ti * 64;
    int tid = threadIdx.x;
    int r = tid >> 2, koff = (tid & 3) * 8;
    int lane = tid & 63, wid = tid >> 6;
    int wy = wid >> 1, wx = wid & 1;
    int quad = lane >> 4, l15 = lane & 15;
    f32x4 acc[2][2] = {};
    for (int kk = 0; kk < KCHUNK; kk += 32) {
        int kg = chunk * KCHUNK + kk + koff;
        const float4* pa = (const float4*)(q + taddr(b, s0 + r, kg));
        *(u32x4*)&lds_a[r * 40 + koff] = pack8(pa[0], pa[1]);
        const float4* pb = (const float4*)(kmat + taddr(b, t0 + r, kg));
        *(u32x4*)&lds_b[r * 40 + koff] = pack8(pb[0], pb[1]);
        __syncthreads();
        bf16x8 af[2], bf[2];
#pragma unroll
        for (int t = 0; t < 2; ++t) {
            af[t] = __builtin_bit_cast(bf16x8,
                *(const u32x4*)&lds_a[(wy * 32 + t * 16 + l15) * 40 + quad * 8]);
            bf[t] = __builtin_bit_cast(bf16x8,
                *(const u32x4*)&lds_b[(wx * 32 + t * 16 + l15) * 40 + quad * 8]);
        }
#pragma unroll
        for (int tm = 0; tm < 2; ++tm)
#pragma unroll
            for (int tn = 0; tn < 2; ++tn)
                acc[tm][tn] = __builtin_amdgcn_mfma_f32_16x16x32_bf16(
                    af[tm], bf[tn], acc[tm][tn], 0, 0, 0);
        __syncthreads();
    }
#pragma unroll
    for (int tm = 0; tm < 2; ++tm)
#pragma unroll
        for (int tn = 0; tn < 2; ++tn)
#pragma unroll
            for (int i = 0; i < 4; ++i) {
                int s = s0 + wy * 32 + tm * 16 + quad * 4 + i;
                int t = t0 + wx * 32 + tn * 16 + l15;
                if (t <= s) {
                    float val = acc[tm][tn][i] * qinv[b * 320 + s] * kinv[b * 320 + t];
                    atomicAdd(&att[(b * 320 + s) * 320 + t], val);
                }
            }
}

__global__ __launch_bounds__(256) void pv_kernel(
        const unsigned short* __restrict__ p, const float* __restrict__ vin,
        float* __restrict__ out) {
    __shared__ unsigned short lds_a[64 * 40];
    __shared__ unsigned short lds_b[64 * 40];
    int b = blockIdx.z;
    int s0 = blockIdx.y * 64;
    int d0 = blockIdx.x * 64;
    int tid = threadIdx.x;
    int lane = tid & 63, wid = tid >> 6;
    int wy = wid >> 1, wx = wid & 1;
    int quad = lane >> 4, l15 = lane & 15;
    int ar = tid >> 2, akoff = (tid & 3) * 8;
    int bt = tid >> 4;
    int bd = (tid & 15) * 4;
    f32x4 acc[2][2] = {};
    int nk = (s0 + 64) >> 5;
    for (int kc = 0; kc < nk; ++kc) {
        int t0k = kc * 32;
        u32x4 aw = *(const u32x4*)(p + ((b * 320 + s0 + ar) * 320 + t0k + akoff));
        *(u32x4*)&lds_a[ar * 40 + akoff] = aw;
#pragma unroll
        for (int pp = 0; pp < 2; ++pp) {
            int tt = bt + pp * 16;
            float4 v = *(const float4*)(vin + taddr(b, t0k + tt, d0 + bd));
            lds_b[(bd + 0) * 40 + tt] = f2bf(v.x);
            lds_b[(bd + 1) * 40 + tt] = f2bf(v.y);
            lds_b[(bd + 2) * 40 + tt] = f2bf(v.z);
            lds_b[(bd + 3) * 40 + tt] = f2bf(v.w);
        }
        __syncthreads();
        bf16x8 af[2], bf[2];
#pragma unroll
        for (int t = 0; t < 2; ++t) {
            af[t] = __builtin_bit_cast(bf16x8,
                *(const u32x4*)&lds_a[(wy * 32 + t * 16 + l15) * 40 + quad * 8]);
            bf[t] = __builtin_bit_cast(bf16x8,
                *(const u32x4*)&lds_b[(wx * 32 + t * 16 + l15) * 40 + quad * 8]);
        }
#pragma unroll
        for (int tm = 0; tm < 2; ++tm)
#pragma unroll
            for (int tn = 0; tn < 2; ++tn)
                acc[tm][tn] = __builtin_amdgcn_mfma_f32_16x16x32_bf16(
                    af[tm], bf[tn], acc[tm][tn], 0, 0, 0);
        __syncthreads();
    }
#pragma unroll
    for (int tm = 0; tm < 2; ++tm)
#pragma unroll
        for (int tn = 0; tn < 2; ++tn)
#pragma unroll
            for (int i = 0; i < 4; ++i) {
                int s = s0 + wy * 32 + tm * 16 + quad * 4 + i;
                int d = d0 + wx * 32 + tn * 16 + l15;
                int a = taddr(b, s, d);
                out[a] = acc[tm][tn][i] + vin[a];
            }
}

extern "C" void kernel_launch(void* const* d_in, const int* in_sizes, int n_in,
                              void* d_out, int out_size, void* d_ws, size_t ws_size,
                              hipStream_t stream) {
    const float* q = (const float*)d_in[0];
    const float* k = (const float*)d_in[1];
    const float* v = (const float*)d_in[2];
    float* out = (float*)d_out;
    char* ws = (char*)d_ws;

    const size_t QB_BYTES = (size_t)4 * 320 * 20480 * 2;     // 52,428,800
    const size_t ATT_BYTES = (size_t)4 * 320 * 320 * 4;      // 1,638,400
    const size_t P_BYTES = (size_t)4 * 320 * 320 * 2;        // 819,200
    const size_t INV_BYTES = (size_t)4 * 320 * 4;            // 5,120 per array
    const size_t NEED = 2 * QB_BYTES + ATT_BYTES + P_BYTES + 2 * INV_BYTES;

    if (ws_size >= NEED) {
        unsigned short* qb = (unsigned short*)ws;
        unsigned short* kb = (unsigned short*)(ws + QB_BYTES);
        float* att = (float*)(ws + 2 * QB_BYTES);
        unsigned short* p = (unsigned short*)(ws + 2 * QB_BYTES + ATT_BYTES);
        float* qinv = (float*)(ws + 2 * QB_BYTES + ATT_BYTES + P_BYTES);
        float* kinv = (float*)(ws + 2 * QB_BYTES + ATT_BYTES + P_BYTES + INV_BYTES);
        unsigned short* vT = (unsigned short*)ws;  // overlaps qb; written after scores2

        qk_prep_kernel<<<2560, 1024, 0, stream>>>(q, k, qb, kb, qinv, kinv);
        hipMemsetAsync(att, 0, ATT_BYTES, stream);
        scores2_kernel<<<dim3(15 * SPLIT, 4), 256, 0, stream>>>(qb, kb, qinv, kinv, att);
        softmax_vprep_kernel<<<6720, 256, 0, stream>>>(att, p, v, vT);
        pv2_kernel<<<dim3(320, 5, 4), 256, 0, stream>>>(p, vT, v, out);
    } else {
        float* qinv = (float*)ws;
        float* kinv = (float*)(ws + 5120);
        float* att = (float*)(ws + 10240);
        unsigned short* p = (unsigned short*)(ws + 10240 + ATT_BYTES);

        norm_kernel<<<2560, 256, 0, stream>>>(q, k, qinv, kinv);
        hipMemsetAsync(att, 0, ATT_BYTES, stream);
        scores_kernel<<<dim3(15 * CHUNKS, 4), 256, 0, stream>>>(q, k, qinv, kinv, att);
        softmax_kernel<<<320, 256, 0, stream>>>(att, p);
        pv_kernel<<<dim3(320, 5, 4), 256, 0, stream>>>(p, v, out);
    }
}